// Round 13
// baseline (333.036 us; speedup 1.0000x reference)
//
#include <hip/hip_runtime.h>
#include <hip/hip_fp16.h>

#define ND 64
#define BG 256        // dst ids per bucket
#define MAXB 512      // max buckets (LDS sizing); nb = ceil(2N/BG) = 391
#define PCH 16384     // edges per partition chunk: 196 part-blocks
#define CAP 9216      // per-bucket slab capacity; lambda=8184, sigma~90 -> 11-sigma margin

__device__ __forceinline__ float lrelu(float x) { return x > 0.f ? x : 0.2f * x; }

__device__ __forceinline__ float wave_sum(float v) {
#pragma unroll
    for (int m = 32; m > 0; m >>= 1) v += __shfl_xor(v, m, 64);
    return v;
}

// 8 fp16 x fp32 fused into 8 fp32 accumulators (v_fma_mix-friendly scalar form)
__device__ __forceinline__ void fma8(float* acc, float w, int4 raw) {
    union { int4 i; __half h[8]; } u;
    u.i = raw;
#pragma unroll
    for (int i = 0; i < 8; i++) acc[i] = fmaf(w, __half2float(u.h[i]), acc[i]);
}

// ---------------- bucketed CSR build (fixed-capacity slabs) ----------------
__global__ void init_cursor(int* __restrict__ bcursor, int nb) {
    int t = threadIdx.x;
    if (t < nb) bcursor[t] = t * CAP;
}

// ---- partition body: multi-split into reserved runs; entry (src<<8 | idx&255) ----
// Fast path (full chunk): 16 edges/thread stashed in registers across passes.
__device__ void partition_body(int* hist, int* lcur,
                               const int* __restrict__ eI, const int* __restrict__ eP,
                               int* __restrict__ bcursor, int* __restrict__ part,
                               int N, int E, int nb) {
    int t = threadIdx.x;
    int total = 2 * E;
    int chunkBase = blockIdx.x * PCH;
    int cnt = min(PCH, total - chunkBase);
    if (t < nb) hist[t] = 0;
    __syncthreads();

    if (cnt == PCH) {
        int pk[16];
        unsigned bkp[8];
#pragma unroll
        for (int it = 0; it < 4; it++) {
            int i = t * 4 + it * 4096;
            int e = chunkBase + i;
            int sv[4], dv[4];
            if (e + 3 < E) {
                int4 a = *(const int4*)(eI + e);
                int4 b = *(const int4*)(eI + E + e);
                sv[0] = a.x; sv[1] = a.y; sv[2] = a.z; sv[3] = a.w;
                dv[0] = b.x; dv[1] = b.y; dv[2] = b.z; dv[3] = b.w;
            } else if (e >= E) {
                int4 a = *(const int4*)(eP + (e - E));
                int4 b = *(const int4*)(eP + E + (e - E));
                sv[0] = a.x; sv[1] = a.y; sv[2] = a.z; sv[3] = a.w;
                dv[0] = b.x + N; dv[1] = b.y + N; dv[2] = b.z + N; dv[3] = b.w + N;
            } else {
#pragma unroll
                for (int k = 0; k < 4; k++) {
                    int ee = e + k;
                    if (ee < E) { sv[k] = eI[ee]; dv[k] = eI[E + ee]; }
                    else        { sv[k] = eP[ee - E]; dv[k] = N + eP[E + ee - E]; }
                }
            }
#pragma unroll
            for (int k = 0; k < 4; k++) {
                int j = it * 4 + k;
                int bk = dv[k] >> 8;
                pk[j] = (sv[k] << 8) | (dv[k] & 255);
                atomicAdd(&hist[bk], 1);
                if ((j & 1) == 0) bkp[j >> 1] = (unsigned)bk;
                else bkp[j >> 1] |= (unsigned)bk << 16;
            }
        }
        __syncthreads();
        if (t < nb) lcur[t] = hist[t] ? atomicAdd(&bcursor[t], hist[t]) : 0;
        __syncthreads();
#pragma unroll
        for (int j = 0; j < 16; j++) {
            int bk = (bkp[j >> 1] >> ((j & 1) * 16)) & 0xffff;
            int pos = atomicAdd(&lcur[bk], 1);
            part[pos] = pk[j];
        }
        return;
    }

    // slow path (tail chunk only)
    int cnt4 = cnt & ~3;
    for (int i = t * 4; i < cnt4; i += 4096) {
        int e = chunkBase + i;
        int4 d; int base;
        if (e + 3 < E)   { d = *(const int4*)(eI + E + e); base = 0; }
        else if (e >= E) { d = *(const int4*)(eP + E + (e - E)); base = N; }
        else {
            int tmp[4];
#pragma unroll
            for (int k = 0; k < 4; k++) {
                int ee = e + k;
                tmp[k] = (ee < E) ? eI[E + ee] : N + eP[E + ee - E];
            }
            d = make_int4(tmp[0], tmp[1], tmp[2], tmp[3]); base = 0;
        }
        atomicAdd(&hist[(base + d.x) >> 8], 1);
        atomicAdd(&hist[(base + d.y) >> 8], 1);
        atomicAdd(&hist[(base + d.z) >> 8], 1);
        atomicAdd(&hist[(base + d.w) >> 8], 1);
    }
    for (int i = cnt4 + t; i < cnt; i += 1024) {
        int e = chunkBase + i;
        int idx = (e < E) ? eI[E + e] : N + eP[E + (e - E)];
        atomicAdd(&hist[idx >> 8], 1);
    }
    __syncthreads();
    if (t < nb) lcur[t] = hist[t] ? atomicAdd(&bcursor[t], hist[t]) : 0;
    __syncthreads();
    for (int i = t; i < cnt; i += 1024) {
        int e = chunkBase + i;
        int s, idx;
        if (e < E) { s = eI[e]; idx = eI[E + e]; }
        else       { s = eP[e - E]; idx = N + eP[E + (e - E)]; }
        int pos = atomicAdd(&lcur[idx >> 8], 1);
        part[pos] = (s << 8) | (idx & 255);
    }
}

// ---- gemm body: h(fp16) = x @ W + score dots; 16 waves/block, 4 nodes/wave ----
__device__ void gemm_body(float* xsAll, int gb,
                          const float* __restrict__ xA, const float* __restrict__ xB,
                          const float* __restrict__ WA, const float* __restrict__ WB,
                          const float* __restrict__ asA, const float* __restrict__ adA,
                          const float* __restrict__ asB, const float* __restrict__ adB,
                          __half* __restrict__ h16, float* __restrict__ ssrc,
                          float* __restrict__ sdst, int N) {
    int half = gb & 1;
    int blk = gb >> 1;
    int wave = threadIdx.x >> 6;
    int lane = threadIdx.x & 63;
    const float* x  = half ? xB : xA;
    const float* W  = half ? WB : WA;
    const float* av_ = half ? asB : asA;
    const float* dv_ = half ? adB : adA;
    int nodeBase = (blk * 16 + wave) * 4;      // within half
    float* xs = xsAll + wave * (4 * ND);

    if (nodeBase + 3 < N) {
        *(float4*)&xs[lane * 4] = *(const float4*)&x[(size_t)nodeBase * ND + lane * 4];
    } else if (nodeBase < N) {
#pragma unroll
        for (int i = 0; i < 4; i++) {
            int gi = nodeBase * ND + lane * 4 + i;
            xs[lane * 4 + i] = (gi < N * ND) ? x[gi] : 0.f;
        }
    }
    __syncthreads();
    if (nodeBase >= N) return;

    float4 acc = {0.f, 0.f, 0.f, 0.f};
#pragma unroll
    for (int k = 0; k < ND; k++) {
        float wv = W[k * ND + lane];
        acc.x = fmaf(xs[0 * ND + k], wv, acc.x);
        acc.y = fmaf(xs[1 * ND + k], wv, acc.y);
        acc.z = fmaf(xs[2 * ND + k], wv, acc.z);
        acc.w = fmaf(xs[3 * ND + k], wv, acc.w);
    }
    float av = av_[lane], dv = dv_[lane];
    float s1x = wave_sum(acc.x * av), s2x = wave_sum(acc.x * dv);
    float s1y = wave_sum(acc.y * av), s2y = wave_sum(acc.y * dv);
    float s1z = wave_sum(acc.z * av), s2z = wave_sum(acc.z * dv);
    float s1w = wave_sum(acc.w * av), s2w = wave_sum(acc.w * dv);

    int g0 = half * N + nodeBase;
    h16[(size_t)(g0 + 0) * ND + lane] = __float2half(acc.x);
    if (nodeBase + 1 < N) h16[(size_t)(g0 + 1) * ND + lane] = __float2half(acc.y);
    if (nodeBase + 2 < N) h16[(size_t)(g0 + 2) * ND + lane] = __float2half(acc.z);
    if (nodeBase + 3 < N) h16[(size_t)(g0 + 3) * ND + lane] = __float2half(acc.w);
    if (lane == 0) {
        ssrc[g0] = s1x; sdst[g0] = s2x;
        if (nodeBase + 1 < N) { ssrc[g0 + 1] = s1y; sdst[g0 + 1] = s2y; }
        if (nodeBase + 2 < N) { ssrc[g0 + 2] = s1z; sdst[g0 + 2] = s2z; }
        if (nodeBase + 3 < N) { ssrc[g0 + 3] = s1w; sdst[g0 + 3] = s2w; }
    }
}

// ---- fused: partition (blocks < partBlocks) | layer-1 gemm (the rest) ----
__global__ void __launch_bounds__(1024) part_gemm(
        const int* __restrict__ eI, const int* __restrict__ eP,
        int* __restrict__ bcursor, int* __restrict__ part,
        const float* __restrict__ xA, const float* __restrict__ xB,
        const float* __restrict__ WA, const float* __restrict__ WB,
        const float* __restrict__ asA, const float* __restrict__ adA,
        const float* __restrict__ asB, const float* __restrict__ adB,
        __half* __restrict__ h16, float* __restrict__ ssrc, float* __restrict__ sdst,
        int N, int E, int nb, int partBlocks) {
    __shared__ int smem[16 * 4 * ND];   // 16 KB
    if (blockIdx.x < partBlocks) {
        partition_body(smem, smem + MAXB, eI, eP, bcursor, part, N, E, nb);
    } else {
        gemm_body((float*)smem, blockIdx.x - partBlocks,
                  xA, xB, WA, WB, asA, adA, asB, adB, h16, ssrc, sdst, N);
    }
}

// ---------------- standalone dual-graph gemm (layer 2; xA=xB=fused) ----------------
__global__ void gemm_dual(const float* __restrict__ xA, const float* __restrict__ xB,
                          const float* __restrict__ WA, const float* __restrict__ WB,
                          const float* __restrict__ asA, const float* __restrict__ adA,
                          const float* __restrict__ asB, const float* __restrict__ adB,
                          __half* __restrict__ h16, float* __restrict__ ssrc,
                          float* __restrict__ sdst, int N) {
    __shared__ float xs[4][4 * ND];
    int half = blockIdx.x & 1;
    int blk = blockIdx.x >> 1;
    int wave = threadIdx.x >> 6;
    int lane = threadIdx.x & 63;
    const float* x  = half ? xB : xA;
    const float* W  = half ? WB : WA;
    const float* av_ = half ? asB : asA;
    const float* dv_ = half ? adB : adA;
    int nodeBase = (blk * 4 + wave) * 4;
    float* xsw = xs[wave];
    if (nodeBase + 3 < N) {
        *(float4*)&xsw[lane * 4] = *(const float4*)&x[(size_t)nodeBase * ND + lane * 4];
    } else if (nodeBase < N) {
#pragma unroll
        for (int i = 0; i < 4; i++) {
            int gi = nodeBase * ND + lane * 4 + i;
            xsw[lane * 4 + i] = (gi < N * ND) ? x[gi] : 0.f;
        }
    }
    __syncthreads();
    if (nodeBase >= N) return;
    float4 acc = {0.f, 0.f, 0.f, 0.f};
#pragma unroll
    for (int k = 0; k < ND; k++) {
        float wv = W[k * ND + lane];
        acc.x = fmaf(xsw[0 * ND + k], wv, acc.x);
        acc.y = fmaf(xsw[1 * ND + k], wv, acc.y);
        acc.z = fmaf(xsw[2 * ND + k], wv, acc.z);
        acc.w = fmaf(xsw[3 * ND + k], wv, acc.w);
    }
    float av = av_[lane], dv = dv_[lane];
    float s1x = wave_sum(acc.x * av), s2x = wave_sum(acc.x * dv);
    float s1y = wave_sum(acc.y * av), s2y = wave_sum(acc.y * dv);
    float s1z = wave_sum(acc.z * av), s2z = wave_sum(acc.z * dv);
    float s1w = wave_sum(acc.w * av), s2w = wave_sum(acc.w * dv);
    int g0 = half * N + nodeBase;
    h16[(size_t)(g0 + 0) * ND + lane] = __float2half(acc.x);
    if (nodeBase + 1 < N) h16[(size_t)(g0 + 1) * ND + lane] = __float2half(acc.y);
    if (nodeBase + 2 < N) h16[(size_t)(g0 + 2) * ND + lane] = __float2half(acc.z);
    if (nodeBase + 3 < N) h16[(size_t)(g0 + 3) * ND + lane] = __float2half(acc.w);
    if (lane == 0) {
        ssrc[g0] = s1x; sdst[g0] = s2x;
        if (nodeBase + 1 < N) { ssrc[g0 + 1] = s1y; sdst[g0 + 1] = s2y; }
        if (nodeBase + 2 < N) { ssrc[g0 + 2] = s1z; sdst[g0 + 2] = s2z; }
        if (nodeBase + 3 < N) { ssrc[g0 + 3] = s1w; sdst[g0 + 3] = s2w; }
    }
}

// one block (1024 thr) per bucket: per-(dst,src-quartile) hist + wave-shfl scan
// -> row/deg, LDS-cursor scatter (rows come out src-quartile-sorted).
__global__ void bucket_build(const int* __restrict__ part, const int* __restrict__ bcursor,
                             int* __restrict__ row, int* __restrict__ deg,
                             int* __restrict__ csr, int n2, int N) {
    __shared__ int lhist[BG * 4];
    __shared__ int lexc[BG * 4];
    __shared__ int wsum[16];
    int b = blockIdx.x, t = threadIdx.x;   // blockDim == 1024
    int wave = t >> 6, lane = t & 63;
    int start = b * CAP;
    int cnt = bcursor[b] - start;
    int cnt4 = cnt & ~3;
    int q1 = N >> 2, q2 = N >> 1, q3 = q1 + q2;
    auto key = [&](int p) {
        int s = p >> 8;
        int q = (s >= q2) ? 2 : 0;
        q += (s >= (q ? q3 : q1)) ? 1 : 0;
        return ((p & 255) << 2) | q;
    };
    lhist[t] = 0;
    __syncthreads();
    for (int j = t * 4; j < cnt4; j += 4096) {
        int4 p = *(const int4*)(part + start + j);
        atomicAdd(&lhist[key(p.x)], 1);
        atomicAdd(&lhist[key(p.y)], 1);
        atomicAdd(&lhist[key(p.z)], 1);
        atomicAdd(&lhist[key(p.w)], 1);
    }
    for (int j = cnt4 + t; j < cnt; j += 1024) atomicAdd(&lhist[key(part[start + j])], 1);
    __syncthreads();
    int v = lhist[t];
    // wave-level inclusive scan (6 shfl rounds, no barrier)
    int inc = v;
#pragma unroll
    for (int m = 1; m < 64; m <<= 1) {
        int u = __shfl_up(inc, m, 64);
        if (lane >= m) inc += u;
    }
    if (lane == 63) wsum[wave] = inc;
    __syncthreads();
    if (wave == 0) {
        int s = (lane < 16) ? wsum[lane] : 0;
        int si = s;
#pragma unroll
        for (int m = 1; m < 16; m <<= 1) {
            int u = __shfl_up(si, m, 64);
            if (lane >= m) si += u;
        }
        if (lane < 16) wsum[lane] = si - s;        // exclusive wave offsets
    }
    __syncthreads();
    int excl = inc - v + wsum[wave];
    lexc[t] = excl;
    __syncthreads();
    if (t < BG) {
        int g = b * BG + t;
        if (g < n2) {
            row[g] = start + lexc[4 * t];
            deg[g] = lhist[4 * t] + lhist[4 * t + 1] + lhist[4 * t + 2] + lhist[4 * t + 3];
        }
    }
    __syncthreads();
    lhist[t] = start + excl;          // reuse as global write cursor
    __syncthreads();
    for (int j = t * 4; j < cnt4; j += 4096) {
        int4 p = *(const int4*)(part + start + j);
        int pos;
        pos = atomicAdd(&lhist[key(p.x)], 1); csr[pos] = p.x >> 8;
        pos = atomicAdd(&lhist[key(p.y)], 1); csr[pos] = p.y >> 8;
        pos = atomicAdd(&lhist[key(p.z)], 1); csr[pos] = p.z >> 8;
        pos = atomicAdd(&lhist[key(p.w)], 1); csr[pos] = p.w >> 8;
    }
    for (int j = cnt4 + t; j < cnt; j += 1024) {
        int p = part[start + j];
        int pos = atomicAdd(&lhist[key(p)], 1);
        csr[pos] = p >> 8;
    }
}

// ---------------- aggregate + fused branch attention ----------------
// Block covers 8 nodes x BOTH halves: waves 0,1 = graph I, waves 2,3 = graph P.
// Accumulation: 16-lane group per (half,node), unroll-8 gather pipeline.
// Epilogue: 4 KB LDS tile exchange, block computes the softmax2 blend.
// mode 1: out = fused rows [N x ND] (with relu before blend).
// mode 2: out = final MLP output [N] (blend -> mlp dot).
__global__ void aggregate_fused(const int* __restrict__ csr, const int* __restrict__ row,
                                const int* __restrict__ deg, const float* __restrict__ ssrc,
                                const float* __restrict__ sdst, const __half* __restrict__ h16,
                                const float* __restrict__ bA, const float* __restrict__ bB,
                                const float* __restrict__ att, const float* __restrict__ mlpw,
                                const float* __restrict__ mlpb, float* __restrict__ outp,
                                int N, int mode) {
    __shared__ float lds[2][8][ND];
    int wave = threadIdx.x >> 6;      // 0..3
    int lane = threadIdx.x & 63;
    int half = wave >> 1;             // waves 0,1 -> I; 2,3 -> P
    int sub  = lane >> 4;
    int l16  = lane & 15;
    int slot = l16 >> 3;
    int fl8  = (l16 & 7) * 8;
    int ln   = (wave & 1) * 4 + sub;  // local node 0..7
    int node = blockIdx.x * 8 + ln;
    bool valid = node < N;
    int g = half * N + node;
    const float* bias = half ? bB : bA;
    const float* ss = ssrc + (size_t)half * N;
    const __half* hh = h16 + (size_t)half * N * ND;

    int start = valid ? row[g] : 0;
    int cnt   = valid ? deg[g] : 0;
    float sd  = valid ? sdst[g] : 0.f;
    float wself = valid ? __expf(lrelu(ss[node] + sd)) : 0.f;

    float acc[8] = {0.f, 0.f, 0.f, 0.f, 0.f, 0.f, 0.f, 0.f};
    float denomp = 0.f;
    int waveBase = sub << 4;

    // chunk 0 prologue
    int c16 = min(16, cnt);
    int sj = (l16 < c16) ? csr[start + l16] : 0;
    float wj = (l16 < c16) ? __expf(lrelu(ss[sj] + sd)) : 0.f;

    for (int base = 0; base < cnt; base += 16) {
        // prefetch next chunk's indices + raw scores
        int nb2 = base + 16;
        int sjn = 0; float svn = 0.f; int c16n = cnt - nb2;
        if (nb2 < cnt) {
            sjn = (l16 < c16n) ? csr[start + nb2 + l16] : 0;
            svn = (l16 < c16n) ? ss[sjn] : 0.f;
        }
        denomp += wj;
        // broadcast all 8 (w,s) pairs, then issue all 8 gathers back-to-back
        float w[8]; int s[8];
#pragma unroll
        for (int c = 0; c < 8; c++) {
            w[c] = __shfl(wj, waveBase + 2 * c + slot, 64);
            s[c] = __shfl(sj, waveBase + 2 * c + slot, 64);
        }
        int4 r[8];
#pragma unroll
        for (int c = 0; c < 8; c++)
            r[c] = *(const int4*)(hh + (size_t)s[c] * ND + fl8);
#pragma unroll
        for (int c = 0; c < 8; c++) fma8(acc, w[c], r[c]);
        if (nb2 < cnt) {
            wj = (l16 < c16n) ? __expf(lrelu(svn + sd)) : 0.f;
            sj = sjn;
        }
    }

    // combine the 2 slots; denom over the 16-lane group
#pragma unroll
    for (int i = 0; i < 8; i++) acc[i] += __shfl_xor(acc[i], 8, 64);
#pragma unroll
    for (int m = 1; m <= 8; m <<= 1) denomp += __shfl_xor(denomp, m, 64);
    float denom = denomp + wself;

    if (valid && slot == 0) {
        int4 rawS = *(const int4*)(hh + (size_t)node * ND + fl8);
        union { int4 i; __half h[8]; } us;
        us.i = rawS;
        float v[8];
#pragma unroll
        for (int i = 0; i < 8; i++)
            v[i] = (acc[i] + wself * __half2float(us.h[i])) / denom + bias[fl8 + i];
        if (mode == 1) {
#pragma unroll
            for (int i = 0; i < 8; i++) v[i] = fmaxf(v[i], 0.f);
        }
        *(float4*)&lds[half][ln][fl8]     = make_float4(v[0], v[1], v[2], v[3]);
        *(float4*)&lds[half][ln][fl8 + 4] = make_float4(v[4], v[5], v[6], v[7]);
    }
    __syncthreads();

    // blend stage: wave handles 2 nodes (lanes 0-31 / 32-63), 2 cols per lane
    int bn = wave * 2 + (lane >> 5);
    int node2 = blockIdx.x * 8 + bn;
    if (node2 >= N) return;
    int c = (lane & 31) * 2;
    float2 hi = *(float2*)&lds[0][bn][c];
    float2 hp = *(float2*)&lds[1][bn][c];
    float p0 = att[c] * hi.x + att[c + 1] * hi.y;
    float p1 = att[ND + c] * hp.x + att[ND + c + 1] * hp.y;
#pragma unroll
    for (int m = 1; m <= 16; m <<= 1) {
        p0 += __shfl_xor(p0, m, 64);
        p1 += __shfl_xor(p1, m, 64);
    }
    float mx = fmaxf(p0, p1);
    float e0 = __expf(p0 - mx), e1 = __expf(p1 - mx);
    float inv = 1.f / (e0 + e1);
    float fx = (e0 * hi.x + e1 * hp.x) * inv;
    float fy = (e0 * hi.y + e1 * hp.y) * inv;
    if (mode == 1) {
        *(float2*)&outp[(size_t)node2 * ND + c] = make_float2(fx, fy);
    } else {
        float o = mlpw[c] * fx + mlpw[c + 1] * fy;
#pragma unroll
        for (int m = 1; m <= 16; m <<= 1) o += __shfl_xor(o, m, 64);
        if ((lane & 31) == 0) outp[node2] = o + mlpb[0];
    }
}

extern "C" void kernel_launch(void* const* d_in, const int* in_sizes, int n_in,
                              void* d_out, int out_size, void* d_ws, size_t ws_size,
                              hipStream_t stream) {
    const int N = in_sizes[0] / ND;   // 50000
    const int E = in_sizes[2] / 2;    // 1600000

    const float* x_ind = (const float*)d_in[0];
    const float* x_pos = (const float*)d_in[1];
    const int*   e_ind = (const int*)d_in[2];
    const int*   e_pos = (const int*)d_in[3];
    const float* w1i = (const float*)d_in[4];
    const float* as1i = (const float*)d_in[5];
    const float* ad1i = (const float*)d_in[6];
    const float* b1i = (const float*)d_in[7];
    const float* w2i = (const float*)d_in[8];
    const float* as2i = (const float*)d_in[9];
    const float* ad2i = (const float*)d_in[10];
    const float* b2i = (const float*)d_in[11];
    const float* w1p = (const float*)d_in[12];
    const float* as1p = (const float*)d_in[13];
    const float* ad1p = (const float*)d_in[14];
    const float* b1p = (const float*)d_in[15];
    const float* w2p = (const float*)d_in[16];
    const float* as2p = (const float*)d_in[17];
    const float* ad2p = (const float*)d_in[18];
    const float* b2p = (const float*)d_in[19];
    const float* fha = (const float*)d_in[20];
    const float* attw = (const float*)d_in[21];
    const float* mlpw = (const float*)d_in[22];
    const float* mlpb = (const float*)d_in[23];

    char* ws = (char*)d_ws;
    size_t off = 0;
    auto alloc = [&](size_t elems) { void* p = ws + off; off += elems * 4; return p; };

    const int n2 = 2 * N;
    const int nb = (n2 + BG - 1) / BG;             // 391

    __half* h16 = (__half*)alloc((size_t)n2 * ND / 2);  // fp16 features, 12.8 MB
    float* fused = (float*)alloc((size_t)N * ND);       // blended layer-1 output, 12.8 MB
    float* ssrc = (float*)alloc(n2);
    float* sdst = (float*)alloc(n2);
    int* deg    = (int*)alloc(n2);
    int* rowi   = (int*)alloc(n2);
    int* csr    = (int*)alloc((size_t)nb * CAP);        // 14.4 MB slabs
    int* part   = (int*)alloc((size_t)nb * CAP);        // 14.4 MB slabs
    int* bcursor= (int*)alloc(MAXB);

    const int partBlocks  = (2 * E + PCH - 1) / PCH;        // 196
    const int gemm1Blocks = 2 * ((N + 63) / 64);            // 1564
    const int gemm2Blocks = 2 * ((N + 15) / 16);            // 6250
    const int aggBlocks   = (N + 7) / 8;                    // 6250

    // ---- CSR build overlapped with layer-1 gemm (independent work) ----
    init_cursor<<<1, 512, 0, stream>>>(bcursor, nb);
    part_gemm<<<partBlocks + gemm1Blocks, 1024, 0, stream>>>(
        e_ind, e_pos, bcursor, part,
        x_ind, x_pos, w1i, w1p, as1i, ad1i, as1p, ad1p,
        h16, ssrc, sdst, N, E, nb, partBlocks);
    bucket_build<<<nb, 1024, 0, stream>>>(part, bcursor, rowi, deg, csr, n2, N);

    // ---- layer 1 aggregate + fused branch attention -> fused rows ----
    aggregate_fused<<<aggBlocks, 256, 0, stream>>>(csr, rowi, deg, ssrc, sdst, h16,
                                                   b1i, b1p, fha, mlpw, mlpb,
                                                   fused, N, 1);

    // ---- layer 2: plain dual gemm on fused rows ----
    gemm_dual<<<gemm2Blocks, 256, 0, stream>>>(fused, fused, w2i, w2p,
                                               as2i, ad2i, as2p, ad2p,
                                               h16, ssrc, sdst, N);

    // ---- layer 2 aggregate + fused branch attention + MLP -> d_out ----
    aggregate_fused<<<aggBlocks, 256, 0, stream>>>(csr, rowi, deg, ssrc, sdst, h16,
                                                   b2i, b2p, attw, mlpw, mlpb,
                                                   (float*)d_out, N, 2);
}

// Round 14
// 329.203 us; speedup vs baseline: 1.0116x; 1.0116x over previous
//
#include <hip/hip_runtime.h>
#include <hip/hip_fp16.h>

#define ND 64
#define BG 256        // dst ids per bucket
#define MAXB 512      // max buckets (LDS sizing); nb = ceil(2N/BG) = 391
#define PCH 16384     // edges per partition chunk: 196 part-blocks
#define CAP 9216      // per-bucket slab capacity; lambda=8184, sigma~90 -> 11-sigma margin

__device__ __forceinline__ float lrelu(float x) { return x > 0.f ? x : 0.2f * x; }

__device__ __forceinline__ float wave_sum(float v) {
#pragma unroll
    for (int m = 32; m > 0; m >>= 1) v += __shfl_xor(v, m, 64);
    return v;
}

// 8 fp16 x fp32 fused into 8 fp32 accumulators (v_fma_mix-friendly scalar form)
__device__ __forceinline__ void fma8(float* acc, float w, int4 raw) {
    union { int4 i; __half h[8]; } u;
    u.i = raw;
#pragma unroll
    for (int i = 0; i < 8; i++) acc[i] = fmaf(w, __half2float(u.h[i]), acc[i]);
}

// ---------------- bucketed CSR build (fixed-capacity slabs) ----------------
__global__ void init_cursor(int* __restrict__ bcursor, int nb) {
    int t = threadIdx.x;
    if (t < nb) bcursor[t] = t * CAP;
}

// ---- partition body: multi-split into reserved runs; entry (src<<8 | idx&255) ----
// Fast path (full chunk): 16 edges/thread stashed in registers across passes.
__device__ void partition_body(int* hist, int* lcur,
                               const int* __restrict__ eI, const int* __restrict__ eP,
                               int* __restrict__ bcursor, int* __restrict__ part,
                               int N, int E, int nb) {
    int t = threadIdx.x;
    int total = 2 * E;
    int chunkBase = blockIdx.x * PCH;
    int cnt = min(PCH, total - chunkBase);
    if (t < nb) hist[t] = 0;
    __syncthreads();

    if (cnt == PCH) {
        int pk[16];
        unsigned bkp[8];
#pragma unroll
        for (int it = 0; it < 4; it++) {
            int i = t * 4 + it * 4096;
            int e = chunkBase + i;
            int sv[4], dv[4];
            if (e + 3 < E) {
                int4 a = *(const int4*)(eI + e);
                int4 b = *(const int4*)(eI + E + e);
                sv[0] = a.x; sv[1] = a.y; sv[2] = a.z; sv[3] = a.w;
                dv[0] = b.x; dv[1] = b.y; dv[2] = b.z; dv[3] = b.w;
            } else if (e >= E) {
                int4 a = *(const int4*)(eP + (e - E));
                int4 b = *(const int4*)(eP + E + (e - E));
                sv[0] = a.x; sv[1] = a.y; sv[2] = a.z; sv[3] = a.w;
                dv[0] = b.x + N; dv[1] = b.y + N; dv[2] = b.z + N; dv[3] = b.w + N;
            } else {
#pragma unroll
                for (int k = 0; k < 4; k++) {
                    int ee = e + k;
                    if (ee < E) { sv[k] = eI[ee]; dv[k] = eI[E + ee]; }
                    else        { sv[k] = eP[ee - E]; dv[k] = N + eP[E + ee - E]; }
                }
            }
#pragma unroll
            for (int k = 0; k < 4; k++) {
                int j = it * 4 + k;
                int bk = dv[k] >> 8;
                pk[j] = (sv[k] << 8) | (dv[k] & 255);
                atomicAdd(&hist[bk], 1);
                if ((j & 1) == 0) bkp[j >> 1] = (unsigned)bk;
                else bkp[j >> 1] |= (unsigned)bk << 16;
            }
        }
        __syncthreads();
        if (t < nb) lcur[t] = hist[t] ? atomicAdd(&bcursor[t], hist[t]) : 0;
        __syncthreads();
#pragma unroll
        for (int j = 0; j < 16; j++) {
            int bk = (bkp[j >> 1] >> ((j & 1) * 16)) & 0xffff;
            int pos = atomicAdd(&lcur[bk], 1);
            part[pos] = pk[j];
        }
        return;
    }

    // slow path (tail chunk only)
    int cnt4 = cnt & ~3;
    for (int i = t * 4; i < cnt4; i += 4096) {
        int e = chunkBase + i;
        int4 d; int base;
        if (e + 3 < E)   { d = *(const int4*)(eI + E + e); base = 0; }
        else if (e >= E) { d = *(const int4*)(eP + E + (e - E)); base = N; }
        else {
            int tmp[4];
#pragma unroll
            for (int k = 0; k < 4; k++) {
                int ee = e + k;
                tmp[k] = (ee < E) ? eI[E + ee] : N + eP[E + ee - E];
            }
            d = make_int4(tmp[0], tmp[1], tmp[2], tmp[3]); base = 0;
        }
        atomicAdd(&hist[(base + d.x) >> 8], 1);
        atomicAdd(&hist[(base + d.y) >> 8], 1);
        atomicAdd(&hist[(base + d.z) >> 8], 1);
        atomicAdd(&hist[(base + d.w) >> 8], 1);
    }
    for (int i = cnt4 + t; i < cnt; i += 1024) {
        int e = chunkBase + i;
        int idx = (e < E) ? eI[E + e] : N + eP[E + (e - E)];
        atomicAdd(&hist[idx >> 8], 1);
    }
    __syncthreads();
    if (t < nb) lcur[t] = hist[t] ? atomicAdd(&bcursor[t], hist[t]) : 0;
    __syncthreads();
    for (int i = t; i < cnt; i += 1024) {
        int e = chunkBase + i;
        int s, idx;
        if (e < E) { s = eI[e]; idx = eI[E + e]; }
        else       { s = eP[e - E]; idx = N + eP[E + (e - E)]; }
        int pos = atomicAdd(&lcur[idx >> 8], 1);
        part[pos] = (s << 8) | (idx & 255);
    }
}

// ---- gemm body: h(fp16) = x @ W + score dots; 16 waves/block, 4 nodes/wave ----
__device__ void gemm_body(float* xsAll, int gb,
                          const float* __restrict__ xA, const float* __restrict__ xB,
                          const float* __restrict__ WA, const float* __restrict__ WB,
                          const float* __restrict__ asA, const float* __restrict__ adA,
                          const float* __restrict__ asB, const float* __restrict__ adB,
                          __half* __restrict__ h16, float* __restrict__ ssrc,
                          float* __restrict__ sdst, int N) {
    int half = gb & 1;
    int blk = gb >> 1;
    int wave = threadIdx.x >> 6;
    int lane = threadIdx.x & 63;
    const float* x  = half ? xB : xA;
    const float* W  = half ? WB : WA;
    const float* av_ = half ? asB : asA;
    const float* dv_ = half ? adB : adA;
    int nodeBase = (blk * 16 + wave) * 4;      // within half
    float* xs = xsAll + wave * (4 * ND);

    if (nodeBase + 3 < N) {
        *(float4*)&xs[lane * 4] = *(const float4*)&x[(size_t)nodeBase * ND + lane * 4];
    } else if (nodeBase < N) {
#pragma unroll
        for (int i = 0; i < 4; i++) {
            int gi = nodeBase * ND + lane * 4 + i;
            xs[lane * 4 + i] = (gi < N * ND) ? x[gi] : 0.f;
        }
    }
    __syncthreads();
    if (nodeBase >= N) return;

    float4 acc = {0.f, 0.f, 0.f, 0.f};
#pragma unroll
    for (int k = 0; k < ND; k++) {
        float wv = W[k * ND + lane];
        acc.x = fmaf(xs[0 * ND + k], wv, acc.x);
        acc.y = fmaf(xs[1 * ND + k], wv, acc.y);
        acc.z = fmaf(xs[2 * ND + k], wv, acc.z);
        acc.w = fmaf(xs[3 * ND + k], wv, acc.w);
    }
    float av = av_[lane], dv = dv_[lane];
    float s1x = wave_sum(acc.x * av), s2x = wave_sum(acc.x * dv);
    float s1y = wave_sum(acc.y * av), s2y = wave_sum(acc.y * dv);
    float s1z = wave_sum(acc.z * av), s2z = wave_sum(acc.z * dv);
    float s1w = wave_sum(acc.w * av), s2w = wave_sum(acc.w * dv);

    int g0 = half * N + nodeBase;
    h16[(size_t)(g0 + 0) * ND + lane] = __float2half(acc.x);
    if (nodeBase + 1 < N) h16[(size_t)(g0 + 1) * ND + lane] = __float2half(acc.y);
    if (nodeBase + 2 < N) h16[(size_t)(g0 + 2) * ND + lane] = __float2half(acc.z);
    if (nodeBase + 3 < N) h16[(size_t)(g0 + 3) * ND + lane] = __float2half(acc.w);
    if (lane == 0) {
        ssrc[g0] = s1x; sdst[g0] = s2x;
        if (nodeBase + 1 < N) { ssrc[g0 + 1] = s1y; sdst[g0 + 1] = s2y; }
        if (nodeBase + 2 < N) { ssrc[g0 + 2] = s1z; sdst[g0 + 2] = s2z; }
        if (nodeBase + 3 < N) { ssrc[g0 + 3] = s1w; sdst[g0 + 3] = s2w; }
    }
}

// ---- fused: partition (blocks < partBlocks) | layer-1 gemm (the rest) ----
__global__ void __launch_bounds__(1024) part_gemm(
        const int* __restrict__ eI, const int* __restrict__ eP,
        int* __restrict__ bcursor, int* __restrict__ part,
        const float* __restrict__ xA, const float* __restrict__ xB,
        const float* __restrict__ WA, const float* __restrict__ WB,
        const float* __restrict__ asA, const float* __restrict__ adA,
        const float* __restrict__ asB, const float* __restrict__ adB,
        __half* __restrict__ h16, float* __restrict__ ssrc, float* __restrict__ sdst,
        int N, int E, int nb, int partBlocks) {
    __shared__ int smem[16 * 4 * ND];   // 16 KB
    if (blockIdx.x < partBlocks) {
        partition_body(smem, smem + MAXB, eI, eP, bcursor, part, N, E, nb);
    } else {
        gemm_body((float*)smem, blockIdx.x - partBlocks,
                  xA, xB, WA, WB, asA, adA, asB, adB, h16, ssrc, sdst, N);
    }
}

// one block (1024 thr) per bucket: per-(dst,src-quartile) hist + wave-shfl scan
// -> row/deg, LDS-cursor scatter (rows come out src-quartile-sorted).
__global__ void bucket_build(const int* __restrict__ part, const int* __restrict__ bcursor,
                             int* __restrict__ row, int* __restrict__ deg,
                             int* __restrict__ csr, int n2, int N) {
    __shared__ int lhist[BG * 4];
    __shared__ int lexc[BG * 4];
    __shared__ int wsum[16];
    int b = blockIdx.x, t = threadIdx.x;   // blockDim == 1024
    int wave = t >> 6, lane = t & 63;
    int start = b * CAP;
    int cnt = bcursor[b] - start;
    int cnt4 = cnt & ~3;
    int q1 = N >> 2, q2 = N >> 1, q3 = q1 + q2;
    auto key = [&](int p) {
        int s = p >> 8;
        int q = (s >= q2) ? 2 : 0;
        q += (s >= (q ? q3 : q1)) ? 1 : 0;
        return ((p & 255) << 2) | q;
    };
    lhist[t] = 0;
    __syncthreads();
    for (int j = t * 4; j < cnt4; j += 4096) {
        int4 p = *(const int4*)(part + start + j);
        atomicAdd(&lhist[key(p.x)], 1);
        atomicAdd(&lhist[key(p.y)], 1);
        atomicAdd(&lhist[key(p.z)], 1);
        atomicAdd(&lhist[key(p.w)], 1);
    }
    for (int j = cnt4 + t; j < cnt; j += 1024) atomicAdd(&lhist[key(part[start + j])], 1);
    __syncthreads();
    int v = lhist[t];
    // wave-level inclusive scan (shfl, no barrier)
    int inc = v;
#pragma unroll
    for (int m = 1; m < 64; m <<= 1) {
        int u = __shfl_up(inc, m, 64);
        if (lane >= m) inc += u;
    }
    if (lane == 63) wsum[wave] = inc;
    __syncthreads();
    if (wave == 0) {
        int s = (lane < 16) ? wsum[lane] : 0;
        int si = s;
#pragma unroll
        for (int m = 1; m < 16; m <<= 1) {
            int u = __shfl_up(si, m, 64);
            if (lane >= m) si += u;
        }
        if (lane < 16) wsum[lane] = si - s;        // exclusive wave offsets
    }
    __syncthreads();
    int excl = inc - v + wsum[wave];
    lexc[t] = excl;
    __syncthreads();
    if (t < BG) {
        int g = b * BG + t;
        if (g < n2) {
            row[g] = start + lexc[4 * t];
            deg[g] = lhist[4 * t] + lhist[4 * t + 1] + lhist[4 * t + 2] + lhist[4 * t + 3];
        }
    }
    __syncthreads();
    lhist[t] = start + excl;          // reuse as global write cursor
    __syncthreads();
    for (int j = t * 4; j < cnt4; j += 4096) {
        int4 p = *(const int4*)(part + start + j);
        int pos;
        pos = atomicAdd(&lhist[key(p.x)], 1); csr[pos] = p.x >> 8;
        pos = atomicAdd(&lhist[key(p.y)], 1); csr[pos] = p.y >> 8;
        pos = atomicAdd(&lhist[key(p.z)], 1); csr[pos] = p.z >> 8;
        pos = atomicAdd(&lhist[key(p.w)], 1); csr[pos] = p.w >> 8;
    }
    for (int j = cnt4 + t; j < cnt; j += 1024) {
        int p = part[start + j];
        int pos = atomicAdd(&lhist[key(p)], 1);
        csr[pos] = p >> 8;
    }
}

// ---------------- layer-2 gemm with fused branch attention ----------------
__global__ void gemm2_fused(const float* __restrict__ hbig, const float* __restrict__ fha,
                            const float* __restrict__ WA, const float* __restrict__ WB,
                            const float* __restrict__ asA, const float* __restrict__ adA,
                            const float* __restrict__ asB, const float* __restrict__ adB,
                            __half* __restrict__ h16, float* __restrict__ ssrc,
                            float* __restrict__ sdst, int N) {
    __shared__ float xs[4][4 * ND];
    int half = blockIdx.x & 1;
    int blk = blockIdx.x >> 1;
    int wave = threadIdx.x >> 6;
    int lane = threadIdx.x & 63;
    const float* W  = half ? WB : WA;
    const float* av_ = half ? asB : asA;
    const float* dv_ = half ? adB : adA;
    int nodeBase = (blk * 4 + wave) * 4;
    float* xsw = xs[wave];

    if (nodeBase < N) {
        int nd = nodeBase + (lane >> 4);           // node this lane stages
        int col = (lane & 15) * 4;
        float4 vi = *(const float4*)&hbig[(size_t)nd * ND + col];
        float4 vp = *(const float4*)&hbig[((size_t)N + nd) * ND + col];
        float4 a0 = *(const float4*)&fha[col];
        float4 a1 = *(const float4*)&fha[ND + col];
        float p0 = vi.x * a0.x + vi.y * a0.y + vi.z * a0.z + vi.w * a0.w;
        float p1 = vp.x * a1.x + vp.y * a1.y + vp.z * a1.z + vp.w * a1.w;
#pragma unroll
        for (int m = 1; m <= 8; m <<= 1) {
            p0 += __shfl_xor(p0, m, 64);
            p1 += __shfl_xor(p1, m, 64);
        }
        float mx = fmaxf(p0, p1);
        float e0 = __expf(p0 - mx), e1 = __expf(p1 - mx);
        float inv = 1.f / (e0 + e1);
        float4 f;
        f.x = (e0 * vi.x + e1 * vp.x) * inv;
        f.y = (e0 * vi.y + e1 * vp.y) * inv;
        f.z = (e0 * vi.z + e1 * vp.z) * inv;
        f.w = (e0 * vi.w + e1 * vp.w) * inv;
        *(float4*)&xsw[lane * 4] = f;
    }
    __syncthreads();
    if (nodeBase >= N) return;

    float4 acc = {0.f, 0.f, 0.f, 0.f};
#pragma unroll
    for (int k = 0; k < ND; k++) {
        float wv = W[k * ND + lane];
        acc.x = fmaf(xsw[0 * ND + k], wv, acc.x);
        acc.y = fmaf(xsw[1 * ND + k], wv, acc.y);
        acc.z = fmaf(xsw[2 * ND + k], wv, acc.z);
        acc.w = fmaf(xsw[3 * ND + k], wv, acc.w);
    }
    float av = av_[lane], dv = dv_[lane];
    float s1x = wave_sum(acc.x * av), s2x = wave_sum(acc.x * dv);
    float s1y = wave_sum(acc.y * av), s2y = wave_sum(acc.y * dv);
    float s1z = wave_sum(acc.z * av), s2z = wave_sum(acc.z * dv);
    float s1w = wave_sum(acc.w * av), s2w = wave_sum(acc.w * dv);

    int g0 = half * N + nodeBase;
    h16[(size_t)(g0 + 0) * ND + lane] = __float2half(acc.x);
    h16[(size_t)(g0 + 1) * ND + lane] = __float2half(acc.y);
    h16[(size_t)(g0 + 2) * ND + lane] = __float2half(acc.z);
    h16[(size_t)(g0 + 3) * ND + lane] = __float2half(acc.w);
    if (lane == 0) {
        ssrc[g0] = s1x; sdst[g0] = s2x;
        ssrc[g0 + 1] = s1y; sdst[g0 + 1] = s2y;
        ssrc[g0 + 2] = s1z; sdst[g0 + 2] = s2z;
        ssrc[g0 + 3] = s1w; sdst[g0 + 3] = s2w;
    }
}

// ---------------- dual-graph aggregate: 4 nodes/wave, parity half split,
// batch-4 gather pipeline (4 int4 gathers in flight per lane) ----------------
__global__ void aggregate_dual(const int* __restrict__ csr, const int* __restrict__ row,
                               const int* __restrict__ deg, const float* __restrict__ ssrc,
                               const float* __restrict__ sdst, const __half* __restrict__ h16,
                               const float* __restrict__ bA, const float* __restrict__ bB,
                               float* __restrict__ out, int N, int relu) {
    int half = blockIdx.x & 1;
    int wave = threadIdx.x >> 6;
    int lane = threadIdx.x & 63;
    int sub  = lane >> 4;             // which of the 4 nodes this lane serves
    int l16  = lane & 15;             // lane within the 16-lane group
    int slot = l16 >> 3;              // edge slot 0/1
    int fl8  = (l16 & 7) * 8;         // 8 halves owned by this lane
    int node = ((blockIdx.x >> 1) * 4 + wave) * 4 + sub;   // within half
    bool valid = node < N;
    int g = half * N + node;
    const float* bias = half ? bB : bA;
    const float* ss = ssrc + (size_t)half * N;       // per-half score table
    const __half* hh = h16 + (size_t)half * N * ND;  // per-half feature table

    int start = valid ? row[g] : 0;
    int cnt   = valid ? deg[g] : 0;
    float sd  = valid ? sdst[g] : 0.f;
    float wself = valid ? __expf(lrelu(ss[node] + sd)) : 0.f;

    float acc[8] = {0.f, 0.f, 0.f, 0.f, 0.f, 0.f, 0.f, 0.f};
    float denomp = 0.f;
    int waveBase = sub << 4;

    // chunk 0 prologue (masked lanes -> row 0, weight 0)
    int c16 = min(16, cnt);
    int sj = (l16 < c16) ? csr[start + l16] : 0;
    float wj = (l16 < c16) ? __expf(lrelu(ss[sj] + sd)) : 0.f;

    for (int base = 0; base < cnt; base += 16) {
        // prefetch next chunk's indices + raw scores
        int nb2 = base + 16;
        int sjn = 0; float svn = 0.f; int c16n = cnt - nb2;
        if (nb2 < cnt) {
            sjn = (l16 < c16n) ? csr[start + nb2 + l16] : 0;
            svn = (l16 < c16n) ? ss[sjn] : 0.f;
        }
        denomp += wj;
        // 2 batches of 4: broadcast 4 (w,s), issue 4 gathers, then 4 fma8
#pragma unroll
        for (int cb = 0; cb < 2; cb++) {
            float w[4]; int s[4];
#pragma unroll
            for (int k = 0; k < 4; k++) {
                int c = cb * 4 + k;
                w[k] = __shfl(wj, waveBase + 2 * c + slot, 64);
                s[k] = __shfl(sj, waveBase + 2 * c + slot, 64);
            }
            int4 r[4];
#pragma unroll
            for (int k = 0; k < 4; k++)
                r[k] = *(const int4*)(hh + (size_t)s[k] * ND + fl8);
#pragma unroll
            for (int k = 0; k < 4; k++) fma8(acc, w[k], r[k]);
        }
        if (nb2 < cnt) {
            wj = (l16 < c16n) ? __expf(lrelu(svn + sd)) : 0.f;
            sj = sjn;
        }
    }

    // combine the 2 slots; denom over the 16-lane group
#pragma unroll
    for (int i = 0; i < 8; i++) acc[i] += __shfl_xor(acc[i], 8, 64);
#pragma unroll
    for (int m = 1; m <= 8; m <<= 1) denomp += __shfl_xor(denomp, m, 64);
    float denom = denomp + wself;

    if (!valid || slot != 0) return;
    // self contribution + epilogue (8 lanes per group, 8 cols each)
    int4 rawS = *(const int4*)(hh + (size_t)node * ND + fl8);
    union { int4 i; __half h[8]; } us;
    us.i = rawS;
    float v[8];
#pragma unroll
    for (int i = 0; i < 8; i++)
        v[i] = (acc[i] + wself * __half2float(us.h[i])) / denom + bias[fl8 + i];
    if (relu) {
#pragma unroll
        for (int i = 0; i < 8; i++) v[i] = fmaxf(v[i], 0.f);
    }
    *(float4*)&out[(size_t)g * ND + fl8]     = make_float4(v[0], v[1], v[2], v[3]);
    *(float4*)&out[(size_t)g * ND + fl8 + 4] = make_float4(v[4], v[5], v[6], v[7]);
}

// branch attention + final 64->1 MLP
__global__ void branch_att_mlp(const float* __restrict__ hbig, const float* __restrict__ att,
                               const float* __restrict__ mlpw, const float* __restrict__ mlpb,
                               float* __restrict__ out, int n) {
    int gid = blockIdx.x * blockDim.x + threadIdx.x;
    int node = gid >> 6, lane = gid & 63;
    if (node >= n) return;
    float vi = hbig[(size_t)node * ND + lane];
    float vp = hbig[((size_t)n + node) * ND + lane];
    float s0 = wave_sum(att[lane] * vi);
    float s1 = wave_sum(att[ND + lane] * vp);
    float m = fmaxf(s0, s1);
    float a0 = __expf(s0 - m), a1 = __expf(s1 - m);
    float xj = (a0 * vi + a1 * vp) / (a0 + a1);
    float o = wave_sum(xj * mlpw[lane]);
    if (lane == 0) out[node] = o + mlpb[0];
}

extern "C" void kernel_launch(void* const* d_in, const int* in_sizes, int n_in,
                              void* d_out, int out_size, void* d_ws, size_t ws_size,
                              hipStream_t stream) {
    const int N = in_sizes[0] / ND;   // 50000
    const int E = in_sizes[2] / 2;    // 1600000

    const float* x_ind = (const float*)d_in[0];
    const float* x_pos = (const float*)d_in[1];
    const int*   e_ind = (const int*)d_in[2];
    const int*   e_pos = (const int*)d_in[3];
    const float* w1i = (const float*)d_in[4];
    const float* as1i = (const float*)d_in[5];
    const float* ad1i = (const float*)d_in[6];
    const float* b1i = (const float*)d_in[7];
    const float* w2i = (const float*)d_in[8];
    const float* as2i = (const float*)d_in[9];
    const float* ad2i = (const float*)d_in[10];
    const float* b2i = (const float*)d_in[11];
    const float* w1p = (const float*)d_in[12];
    const float* as1p = (const float*)d_in[13];
    const float* ad1p = (const float*)d_in[14];
    const float* b1p = (const float*)d_in[15];
    const float* w2p = (const float*)d_in[16];
    const float* as2p = (const float*)d_in[17];
    const float* ad2p = (const float*)d_in[18];
    const float* b2p = (const float*)d_in[19];
    const float* fha = (const float*)d_in[20];
    const float* attw = (const float*)d_in[21];
    const float* mlpw = (const float*)d_in[22];
    const float* mlpb = (const float*)d_in[23];

    char* ws = (char*)d_ws;
    size_t off = 0;
    auto alloc = [&](size_t elems) { void* p = ws + off; off += elems * 4; return p; };

    const int n2 = 2 * N;
    const int nb = (n2 + BG - 1) / BG;             // 391

    __half* h16 = (__half*)alloc((size_t)n2 * ND / 2);  // fp16 features both halves, 12.8 MB
    float* hbig = (float*)alloc((size_t)n2 * ND);       // layer outputs [I; P], 25.6 MB
    float* ssrc = (float*)alloc(n2);
    float* sdst = (float*)alloc(n2);
    int* deg    = (int*)alloc(n2);
    int* rowi   = (int*)alloc(n2);
    int* csr    = (int*)alloc((size_t)nb * CAP);        // 14.4 MB slabs
    int* bcursor= (int*)alloc(MAXB);
    // part[nb*CAP] ints alias hbig (25.6 MB >= 14.4 MB) — consumed by
    // bucket_build before the first aggregate_dual writes hbig
    int* part   = (int*)hbig;

    const int partBlocks  = (2 * E + PCH - 1) / PCH;        // 196
    const int gemm1Blocks = 2 * ((N + 63) / 64);            // 1564
    const int gemm2Blocks = 2 * ((N + 15) / 16);            // 6250
    const int aggBlocks   = 2 * ((N + 15) / 16);            // 6250
    const int nodeBlocks  = (N + 3) / 4;                    // 12500

    // ---- CSR build overlapped with layer-1 gemm (independent work) ----
    init_cursor<<<1, 512, 0, stream>>>(bcursor, nb);
    part_gemm<<<partBlocks + gemm1Blocks, 1024, 0, stream>>>(
        e_ind, e_pos, bcursor, part,
        x_ind, x_pos, w1i, w1p, as1i, ad1i, as1p, ad1p,
        h16, ssrc, sdst, N, E, nb, partBlocks);
    bucket_build<<<nb, 1024, 0, stream>>>(part, bcursor, rowi, deg, csr, n2, N);

    // ---- layer 1 aggregate ----
    aggregate_dual<<<aggBlocks, 256, 0, stream>>>(csr, rowi, deg, ssrc, sdst, h16,
                                                  b1i, b1p, hbig, N, 1);

    // ---- layer 2 (branch attention fused into the gemm) ----
    gemm2_fused<<<gemm2Blocks, 256, 0, stream>>>(hbig, fha, w2i, w2p,
                                                 as2i, ad2i, as2p, ad2p,
                                                 h16, ssrc, sdst, N);
    aggregate_dual<<<aggBlocks, 256, 0, stream>>>(csr, rowi, deg, ssrc, sdst, h16,
                                                  b2i, b2p, hbig, N, 0);
    branch_att_mlp<<<nodeBlocks, 256, 0, stream>>>(hbig, attw, mlpw, mlpb,
                                                   (float*)d_out, N);
}